// Round 4
// baseline (219.921 us; speedup 1.0000x reference)
//
#include <hip/hip_runtime.h>
#include <math.h>

// KAN layer forward, MI355X. Uniform-grid cubic B-spline closed form (4-tap
// window at m=floor((x-e0)/h)); boundary/out-of-range handled to match the
// reference's truncated Cox-de Boor recursion.
//
// R3: regular (non-nt) vf4 stores — nt caused +32MB HBM write amplification.
// coef taps gathered from global memory (L1/L2-hit) with STATIC w[] indexing —
// R2's register-array dynamic indexing exploded VALU (19%->61%).
// Grid 2048 blocks (CO=2 o's, TB=2 batches per thread) = 8 blocks/CU.

#define N_IN   128
#define SIZEK  16384
#define BATCH  512

#define TB 2    // batches per thread
#define CO 2    // o-values per thread

typedef float vf4 __attribute__((ext_vector_type(4)));

__global__ __launch_bounds__(256, 8) void kan_fwd(
    const float* __restrict__ x,            // [512][128]
    const float* __restrict__ scale_b,      // [16384]
    const float* __restrict__ scale_spline, // [16384]
    const float* __restrict__ coef,         // [16384][8]
    const float* __restrict__ mask,         // [16384]
    const float* __restrict__ knots,        // [16384][6]
    float* __restrict__ y,                  // [512][128] (pre-zeroed)
    float* __restrict__ pre_out,            // [512][16384]
    float* __restrict__ spl_out,            // [512][16384]
    float* __restrict__ post_out)           // [512][16384]
{
    const int g  = blockIdx.x * blockDim.x + threadIdx.x;
    const int ig = g & 31;           // i-group: 4 consecutive i
    const int i0 = ig << 2;
    const int r  = g >> 5;
    const int oc = r & 63;           // 64 o-chunks of CO=2
    const int bg = r >> 6;           // 256 batch-groups of TB=2
    const int o0 = oc << 1;
    const int b0 = bg << 1;

    vf4   xv[TB];
    float sil[TB][4];
    float ysum[TB][4];
#pragma unroll
    for (int t = 0; t < TB; ++t) {
        xv[t] = *(const vf4*)&x[(b0 + t) * N_IN + i0];
#pragma unroll
        for (int ii = 0; ii < 4; ++ii) {
            const float xx = xv[t][ii];
            sil[t][ii]  = xx / (1.0f + __expf(-xx));
            ysum[t][ii] = 0.0f;
        }
    }

#pragma unroll
    for (int oo = 0; oo < CO; ++oo) {
        const int o  = o0 + oo;
        const int s0 = (o << 7) | i0;          // 4 consecutive edges

        const vf4 mk4 = *(const vf4*)&mask[s0];
        const vf4 sb4 = *(const vf4*)&scale_b[s0];
        const vf4 ss4 = *(const vf4*)&scale_spline[s0];

        float e0v[4], invh[4];
#pragma unroll
        for (int ii = 0; ii < 4; ++ii) {
            const int s = s0 + ii;
            const float k0 = knots[s * 6];
            const float k5 = knots[s * 6 + 5];
            const float h  = (k5 - k0) * 0.2f;     // (last-first)/G, G=5
            invh[ii] = 1.0f / h;
            e0v[ii]  = k0 - 3.0f * h;              // leftmost extended knot
        }

#pragma unroll
        for (int t = 0; t < TB; ++t) {
            vf4 spl4, post4;
#pragma unroll
            for (int ii = 0; ii < 4; ++ii) {
                const int s = s0 + ii;
                const float u  = (xv[t][ii] - e0v[ii]) * invh[ii];
                const float mf = floorf(u);
                const int   m  = (int)mf;
                const float tt = u - mf;
                const bool inr = (m >= 0) && (m <= 10);

                const float t2  = tt * tt;
                const float t3  = t2 * tt;
                const float omt = 1.0f - tt;
                float w[4];
                w[0] = omt * omt * omt * (1.0f / 6.0f);
                w[1] = (3.0f * t3 - 6.0f * t2 + 4.0f) * (1.0f / 6.0f);
                w[2] = (-3.0f * t3 + 3.0f * t2 + 3.0f * tt + 1.0f) * (1.0f / 6.0f);
                w[3] = t3 * (1.0f / 6.0f);

                const int jlo = m - 3;
                const float* __restrict__ cs = coef + s * 8;
                float spline = 0.0f;
#pragma unroll
                for (int rr = 0; rr < 4; ++rr) {
                    const int j  = jlo + rr;
                    const int jc = min(max(j, 0), 7);      // clamp keeps load in-bounds
                    const float c  = cs[jc];               // L1/L2-hit gather
                    const float wv = (inr && j >= 0 && j <= 7) ? w[rr] : 0.0f;
                    spline = fmaf(c, wv, spline);
                }

                const float splm = spline * mk4[ii];
                const float post = fmaf(sb4[ii], sil[t][ii], ss4[ii] * splm);
                spl4[ii]  = splm;
                post4[ii] = post;
                ysum[t][ii] += post;
            }
            const size_t idx = (size_t)(b0 + t) * SIZEK + (size_t)s0;
            *(vf4*)&pre_out[idx]  = xv[t];
            *(vf4*)&spl_out[idx]  = spl4;
            *(vf4*)&post_out[idx] = post4;
        }
    }

#pragma unroll
    for (int t = 0; t < TB; ++t)
#pragma unroll
        for (int ii = 0; ii < 4; ++ii)
            atomicAdd(&y[(b0 + t) * N_IN + i0 + ii], ysum[t][ii]);
}

extern "C" void kernel_launch(void* const* d_in, const int* in_sizes, int n_in,
                              void* d_out, int out_size, void* d_ws, size_t ws_size,
                              hipStream_t stream) {
    const float* x            = (const float*)d_in[0];
    const float* scale_b      = (const float*)d_in[1];
    const float* scale_spline = (const float*)d_in[2];
    const float* coef         = (const float*)d_in[3];
    const float* mask         = (const float*)d_in[4];
    const float* knots        = (const float*)d_in[5];

    float* out  = (float*)d_out;
    float* y    = out;                         // 512*128
    float* pre  = y + 512 * 128;
    float* spl  = pre + (size_t)512 * 16384;
    float* post = spl + (size_t)512 * 16384;

    (void)hipMemsetAsync(y, 0, 512 * 128 * sizeof(float), stream);

    // threads = 32 i-groups * 64 o-chunks * 256 b-groups = 524288 -> 2048 blocks
    dim3 grid(2048), block(256);
    kan_fwd<<<grid, block, 0, stream>>>(x, scale_b, scale_spline, coef, mask,
                                        knots, y, pre, spl, post);
}

// Round 5
// 165.753 us; speedup vs baseline: 1.3268x; 1.3268x over previous
//
#include <hip/hip_runtime.h>
#include <math.h>

// KAN layer forward, MI355X. Uniform-grid cubic B-spline closed form (4-tap
// window at m=floor((x-e0)/h)); boundary/out-of-range handled to match the
// reference's truncated Cox-de Boor recursion.
//
// R4: bytes back to the 98 MB floor. R3's lesson: duration tracks total HBM
// bytes at ~1.6 TB/s regardless of occupancy/VALU; the 4.19M lane-strided
// global atomics added 88 MiB of EA write traffic. Fix: register-accumulate
// y over CO=4 o's, reduce the block's 8 o-chunks through LDS (plain stores),
// then ONE lane-consecutive global atomicAdd per thread (262K total, ~1 MB).
// Stores stay regular (non-nt) vf4: nt amplified writes (R2), vf4 coalesces
// to full lines. Spline taps gathered from L1/L2 with static w[] indexing
// (register-array dynamic indexing exploded VALU in R2).

#define N_IN   128
#define SIZEK  16384
#define BATCH  512

#define TB 2    // batches per thread
#define CO 4    // o-values per thread

typedef float vf4 __attribute__((ext_vector_type(4)));

__global__ __launch_bounds__(256) void kan_fwd(
    const float* __restrict__ x,            // [512][128]
    const float* __restrict__ scale_b,      // [16384]
    const float* __restrict__ scale_spline, // [16384]
    const float* __restrict__ coef,         // [16384][8]
    const float* __restrict__ mask,         // [16384]
    const float* __restrict__ knots,        // [16384][6]
    float* __restrict__ y,                  // [512][128] (pre-zeroed)
    float* __restrict__ pre_out,            // [512][16384]
    float* __restrict__ spl_out,            // [512][16384]
    float* __restrict__ post_out)           // [512][16384]
{
    // Block-level y partials: [o-chunk-local 8][t 2][i 128]
    __shared__ float yls[8][TB][N_IN];

    const int g  = blockIdx.x * blockDim.x + threadIdx.x;
    const int ig = g & 31;           // i-group: 4 consecutive i
    const int i0 = ig << 2;
    const int r  = g >> 5;
    const int oc = r & 31;           // 32 o-chunks of CO=4
    const int bg = r >> 5;           // 256 batch-groups of TB=2
    const int o0 = oc << 2;
    const int b0 = bg << 1;
    const int ocl = oc & 7;          // o-chunk local to this block (8 per block)

    vf4   xv[TB];
    float sil[TB][4];
    float ysum[TB][4];
#pragma unroll
    for (int t = 0; t < TB; ++t) {
        xv[t] = *(const vf4*)&x[(b0 + t) * N_IN + i0];
#pragma unroll
        for (int ii = 0; ii < 4; ++ii) {
            const float xx = xv[t][ii];
            sil[t][ii]  = xx / (1.0f + __expf(-xx));
            ysum[t][ii] = 0.0f;
        }
    }

#pragma unroll
    for (int oo = 0; oo < CO; ++oo) {
        const int o  = o0 + oo;
        const int s0 = (o << 7) | i0;          // 4 consecutive edges

        const vf4 mk4 = *(const vf4*)&mask[s0];
        const vf4 sb4 = *(const vf4*)&scale_b[s0];
        const vf4 ss4 = *(const vf4*)&scale_spline[s0];

        float e0v[4], invh[4];
#pragma unroll
        for (int ii = 0; ii < 4; ++ii) {
            const int s = s0 + ii;
            const float k0 = knots[s * 6];
            const float k5 = knots[s * 6 + 5];
            const float h  = (k5 - k0) * 0.2f;     // (last-first)/G, G=5
            invh[ii] = 1.0f / h;
            e0v[ii]  = k0 - 3.0f * h;              // leftmost extended knot
        }

#pragma unroll
        for (int t = 0; t < TB; ++t) {
            vf4 spl4, post4;
#pragma unroll
            for (int ii = 0; ii < 4; ++ii) {
                const int s = s0 + ii;
                const float u  = (xv[t][ii] - e0v[ii]) * invh[ii];
                const float mf = floorf(u);
                const int   m  = (int)mf;
                const float tt = u - mf;
                const bool inr = (m >= 0) && (m <= 10);

                const float t2  = tt * tt;
                const float t3  = t2 * tt;
                const float omt = 1.0f - tt;
                float w[4];
                w[0] = omt * omt * omt * (1.0f / 6.0f);
                w[1] = (3.0f * t3 - 6.0f * t2 + 4.0f) * (1.0f / 6.0f);
                w[2] = (-3.0f * t3 + 3.0f * t2 + 3.0f * tt + 1.0f) * (1.0f / 6.0f);
                w[3] = t3 * (1.0f / 6.0f);

                const int jlo = m - 3;
                const float* __restrict__ cs = coef + s * 8;
                float spline = 0.0f;
#pragma unroll
                for (int rr = 0; rr < 4; ++rr) {
                    const int j  = jlo + rr;
                    const int jc = min(max(j, 0), 7);      // clamp keeps load in-bounds
                    const float c  = cs[jc];               // L1/L2-hit gather
                    const float wv = (inr && j >= 0 && j <= 7) ? w[rr] : 0.0f;
                    spline = fmaf(c, wv, spline);
                }

                const float splm = spline * mk4[ii];
                const float post = fmaf(sb4[ii], sil[t][ii], ss4[ii] * splm);
                spl4[ii]  = splm;
                post4[ii] = post;
                ysum[t][ii] += post;
            }
            const size_t idx = (size_t)(b0 + t) * SIZEK + (size_t)s0;
            *(vf4*)&pre_out[idx]  = xv[t];
            *(vf4*)&spl_out[idx]  = spl4;
            *(vf4*)&post_out[idx] = post4;
        }
    }

    // ---- y reduction: registers -> LDS (plain stores) -> 1 atomic/thread ----
#pragma unroll
    for (int t = 0; t < TB; ++t)
        *(vf4*)&yls[ocl][t][i0] = *(vf4*)&ysum[t][0];
    __syncthreads();

    // tid -> (t, i); lanes have consecutive i -> coalesced atomics
    const int tid = threadIdx.x;
    const int t_r = tid >> 7;
    const int i_r = tid & 127;
    float acc = 0.0f;
#pragma unroll
    for (int k = 0; k < 8; ++k)
        acc += yls[k][t_r][i_r];
    atomicAdd(&y[(b0 + t_r) * N_IN + i_r], acc);
}

extern "C" void kernel_launch(void* const* d_in, const int* in_sizes, int n_in,
                              void* d_out, int out_size, void* d_ws, size_t ws_size,
                              hipStream_t stream) {
    const float* x            = (const float*)d_in[0];
    const float* scale_b      = (const float*)d_in[1];
    const float* scale_spline = (const float*)d_in[2];
    const float* coef         = (const float*)d_in[3];
    const float* mask         = (const float*)d_in[4];
    const float* knots        = (const float*)d_in[5];

    float* out  = (float*)d_out;
    float* y    = out;                         // 512*128
    float* pre  = y + 512 * 128;
    float* spl  = pre + (size_t)512 * 16384;
    float* post = spl + (size_t)512 * 16384;

    (void)hipMemsetAsync(y, 0, 512 * 128 * sizeof(float), stream);

    // threads = 32 i-groups * 32 o-chunks * 256 b-groups = 262144 -> 1024 blocks
    dim3 grid(1024), block(256);
    kan_fwd<<<grid, block, 0, stream>>>(x, scale_b, scale_spline, coef, mask,
                                        knots, y, pre, spl, post);
}